// Round 8
// baseline (51.982 us; speedup 1.0000x reference)
//
#include <hip/hip_runtime.h>
#include <hip/hip_bf16.h>

#define L_SEQ 1024
#define D_HEAD 64
#define NT 32          // number of 32-row KV tiles
#define KVBLK 32
#define KSTR 72
#define VSTR 36

typedef __attribute__((ext_vector_type(8))) __bf16 bf16x8;
typedef __attribute__((ext_vector_type(4))) __bf16 bf16x4;
typedef __attribute__((ext_vector_type(4))) float f32x4;
typedef unsigned int u32;

#define STAGE16(gsrc, ldst)                                                     \
  __builtin_amdgcn_global_load_lds(                                             \
      (const __attribute__((address_space(1))) u32*)(gsrc),                     \
      (__attribute__((address_space(3))) u32*)(ldst), 16, 0, 0)

__device__ __forceinline__ float fast_exp2(float x) {
#if __has_builtin(__builtin_amdgcn_exp2f)
    return __builtin_amdgcn_exp2f(x);
#else
    return exp2f(x);
#endif
}

#define MFMA16(a, b, c) __builtin_amdgcn_mfma_f32_16x16x32_bf16((a), (b), (c), 0, 0, 0)

// ---------------------------------------------------------------------------
// Pre-pass (unchanged from round 7): K -> bf16 fragment-permuted +
// XOR-swizzled tile images; V -> bf16 V^T tile images, chunk-swizzled.
// ---------------------------------------------------------------------------
__global__ __launch_bounds__(256) void sdpa_prep(
    const float* __restrict__ K, const float* __restrict__ V,
    __bf16* __restrict__ Kp, __bf16* __restrict__ Vp)
{
    __shared__ float vt[32][68];   // V tile transpose buffer (padded)
    const int tid = threadIdx.x;

    if (blockIdx.x < 4096) {
        // ---- K path: 1M quads
        const int gid = blockIdx.x * 256 + tid;
        const int row = gid >> 4;               // global row (b*1024 + r)
        const int d4  = (gid & 15) << 2;
        f32x4 x = *(const f32x4*)&K[(size_t)row * 64 + d4];
        const int c32 = d4 >> 5, rem = d4 & 31, hf = rem >> 4, h = (rem & 15) >> 2;
        const int cp = ((c32 * 32 + h * 8) ^ ((row & 7) * 8)) + hf * 4;
        bf16x4 o;
        #pragma unroll
        for (int u = 0; u < 4; ++u) o[u] = (__bf16)x[u];
        *(bf16x4*)&Kp[(size_t)row * 64 + cp] = o;
    } else {
        // ---- V path: one 32x64 tile per block, transpose via LDS
        const int T = blockIdx.x - 4096;        // 0..2047
        const float* src = V + (size_t)T * 2048;
        #pragma unroll
        for (int i = 0; i < 2; ++i) {
            int idx = tid + i * 256;
            int r   = idx >> 4;
            int d4  = (idx & 15) << 2;
            f32x4 x = *(const f32x4*)&src[r * 64 + d4];
            vt[r][d4 + 0] = x[0]; vt[r][d4 + 1] = x[1];
            vt[r][d4 + 2] = x[2]; vt[r][d4 + 3] = x[3];
        }
        __syncthreads();
        #pragma unroll
        for (int i = 0; i < 2; ++i) {
            int w = tid + i * 256;
            int d = w >> 3, comb = w & 7, vh = comb >> 1, vhf = comb & 1;
            const int vhs = vh ^ ((d >> 1) & 3);   // chunk swizzle
            bf16x4 o;
            #pragma unroll
            for (int vj = 0; vj < 4; ++vj)
                o[vj] = (__bf16)vt[vhf * 16 + vh * 4 + vj][d];
            *(bf16x4*)&Vp[(size_t)T * 2048 + d * 32 + vhs * 8 + vhf * 4] = o;
        }
    }
}

// ---------------------------------------------------------------------------
// Main: 512 blocks x 4 waves, 32 q-rows/wave. T15 cross-iteration pipeline:
// iteration t runs QK^T(t) MFMAs, exp(t-1) VALU, V(t-1) ds_reads, PV(t-1)
// MFMAs -- all mutually independent, so MFMA/VALU/LDS pipes overlap within
// each wave. 4 LDS buffers (32 KB) so buffer t-1 survives stage(t+2).
// l accumulated via ones-MFMA (no VALU adds, no final shuffle).
// ---------------------------------------------------------------------------
__global__ __launch_bounds__(256) void sdpa_main(
    const float* __restrict__ Q, const __bf16* __restrict__ Kp,
    const __bf16* __restrict__ Vp, float* __restrict__ O)
{
    __shared__ __align__(16) char ldsraw[4 * 8192];   // 4 x (K 4KB + V 4KB)

    const int tid  = threadIdx.x;
    const int lane = tid & 63;
    const int wave = tid >> 6;
    const int li   = lane & 15;
    const int h    = lane >> 4;

    // XCD-chunked swizzle: 64 consecutive logical blocks per XCD.
    const int wg = blockIdx.x;
    const int lb = (wg & 7) * 64 + (wg >> 3);
    const int b  = lb >> 3;          // batch
    const int qt = lb & 7;           // 128-row q-tile
    const int q0 = qt * 128 + wave * 16 + li;   // q-block B rows are q0 + 64

    const float*  Qb = Q  + (size_t)b * L_SEQ * 64;
    const char*   Kb = (const char*)(Kp + (size_t)b * L_SEQ * 64);
    const char*   Vb = (const char*)(Vp + (size_t)b * L_SEQ * 64);

    // ---- Q fragments (both q-blocks): fold (1/temperature)*log2(e)
    const float QSC = 0.18033688011112042f;   // 0.125 * log2(e)
    bf16x8 qA0, qA1, qB0, qB1;
    {
        const float* ra = &Qb[(size_t)q0 * 64];
        const float* rb = &Qb[(size_t)(q0 + 64) * 64];
        f32x4 a00 = *(const f32x4*)&ra[0  + h * 4];
        f32x4 a01 = *(const f32x4*)&ra[16 + h * 4];
        f32x4 a10 = *(const f32x4*)&ra[32 + h * 4];
        f32x4 a11 = *(const f32x4*)&ra[48 + h * 4];
        f32x4 b00 = *(const f32x4*)&rb[0  + h * 4];
        f32x4 b01 = *(const f32x4*)&rb[16 + h * 4];
        f32x4 b10 = *(const f32x4*)&rb[32 + h * 4];
        f32x4 b11 = *(const f32x4*)&rb[48 + h * 4];
        #pragma unroll
        for (int j = 0; j < 4; ++j) {
            qA0[j]     = (__bf16)(a00[j] * QSC);
            qA0[4 + j] = (__bf16)(a01[j] * QSC);
            qA1[j]     = (__bf16)(a10[j] * QSC);
            qA1[4 + j] = (__bf16)(a11[j] * QSC);
            qB0[j]     = (__bf16)(b00[j] * QSC);
            qB0[4 + j] = (__bf16)(b01[j] * QSC);
            qB1[j]     = (__bf16)(b10[j] * QSC);
            qB1[4 + j] = (__bf16)(b11[j] * QSC);
        }
    }

    bf16x8 ones;
    #pragma unroll
    for (int j = 0; j < 8; ++j) ones[j] = (__bf16)1.0f;

    f32x4 oA0 = {0.f,0.f,0.f,0.f}, oA1 = {0.f,0.f,0.f,0.f};
    f32x4 oA2 = {0.f,0.f,0.f,0.f}, oA3 = {0.f,0.f,0.f,0.f};
    f32x4 oB0 = {0.f,0.f,0.f,0.f}, oB1 = {0.f,0.f,0.f,0.f};
    f32x4 oB2 = {0.f,0.f,0.f,0.f}, oB3 = {0.f,0.f,0.f,0.f};
    f32x4 olA = {0.f,0.f,0.f,0.f}, olB = {0.f,0.f,0.f,0.f};

    f32x4 sA0, sA1, sB0, sB1;   // current-tile scores
    f32x4 pA0, pA1, pB0, pB1;   // previous-tile scores (pipeline register)

    auto stage = [&](int t, int bi) {
        const size_t go = (size_t)t * 4096 + (size_t)wave * 1024 + (size_t)(lane << 4);
        STAGE16(Kb + go, ldsraw + bi * 8192 + wave * 1024);
        STAGE16(Vb + go, ldsraw + bi * 8192 + 4096 + wave * 1024);
    };

    const int kswz = (li & 7) << 4;
    const int vswz = ((li >> 1) & 3) << 4;

    // QK^T of tile in buffer bi -> sA*, sB*
    auto qk = [&](int bi) {
        const char* bb = ldsraw + bi * 8192;
        bf16x8 kf00 = *(const bf16x8*)(bb + li * 128 + ((h * 16) ^ kswz));
        bf16x8 kf01 = *(const bf16x8*)(bb + li * 128 + ((64 + h * 16) ^ kswz));
        bf16x8 kf10 = *(const bf16x8*)(bb + 2048 + li * 128 + ((h * 16) ^ kswz));
        bf16x8 kf11 = *(const bf16x8*)(bb + 2048 + li * 128 + ((64 + h * 16) ^ kswz));
        f32x4 z = {0.f, 0.f, 0.f, 0.f};
        __builtin_amdgcn_s_setprio(1);
        sA0 = MFMA16(kf01, qA1, MFMA16(kf00, qA0, z));
        sA1 = MFMA16(kf11, qA1, MFMA16(kf10, qA0, z));
        sB0 = MFMA16(kf01, qB1, MFMA16(kf00, qB0, z));
        sB1 = MFMA16(kf11, qB1, MFMA16(kf10, qB0, z));
        __builtin_amdgcn_s_setprio(0);
    };

    // exp(prev scores) + PV with V fragments from buffer bi (prev tile)
    auto exppv = [&](int bi) {
        bf16x8 pfA, pfB;
        #pragma unroll
        for (int r = 0; r < 4; ++r) {
            pfA[r]     = (__bf16)fast_exp2(pA0[r]);
            pfA[4 + r] = (__bf16)fast_exp2(pA1[r]);
            pfB[r]     = (__bf16)fast_exp2(pB0[r]);
            pfB[4 + r] = (__bf16)fast_exp2(pB1[r]);
        }
        const char* vb = ldsraw + bi * 8192 + 4096;
        bf16x8 vf0 = *(const bf16x8*)(vb + (0 * 16 + li) * 64 + ((h * 16) ^ vswz));
        bf16x8 vf1 = *(const bf16x8*)(vb + (1 * 16 + li) * 64 + ((h * 16) ^ vswz));
        bf16x8 vf2 = *(const bf16x8*)(vb + (2 * 16 + li) * 64 + ((h * 16) ^ vswz));
        bf16x8 vf3 = *(const bf16x8*)(vb + (3 * 16 + li) * 64 + ((h * 16) ^ vswz));
        __builtin_amdgcn_s_setprio(1);
        oA0 = MFMA16(vf0, pfA, oA0);
        oA1 = MFMA16(vf1, pfA, oA1);
        oA2 = MFMA16(vf2, pfA, oA2);
        oA3 = MFMA16(vf3, pfA, oA3);
        olA = MFMA16(ones, pfA, olA);
        oB0 = MFMA16(vf0, pfB, oB0);
        oB1 = MFMA16(vf1, pfB, oB1);
        oB2 = MFMA16(vf2, pfB, oB2);
        oB3 = MFMA16(vf3, pfB, oB3);
        olB = MFMA16(ones, pfB, olB);
        __builtin_amdgcn_s_setprio(0);
    };

    auto rot = [&]() { pA0 = sA0; pA1 = sA1; pB0 = sB0; pB1 = sB1; };

    // ---- prologue: tiles 0,1 in flight; iteration 0 computes QK only
    stage(0, 0);
    stage(1, 1);
    asm volatile("s_waitcnt vmcnt(2)" ::: "memory");   // tile 0 landed
    __builtin_amdgcn_s_barrier();
    stage(2, 2);
    qk(0); rot();

    #pragma unroll 4
    for (int t = 1; t < 30; ++t) {
        asm volatile("s_waitcnt lgkmcnt(0)" ::: "memory");
        asm volatile("s_waitcnt vmcnt(2)" ::: "memory");   // tile t landed
        __builtin_amdgcn_s_barrier();
        stage(t + 2, (t + 2) & 3);   // overwrites buf (t-2): reads drained
        qk(t & 3);                   // QK^T of tile t
        exppv((t - 1) & 3);          // exp + PV of tile t-1 (overlaps QK MFMAs)
        rot();
    }
    // t = 30 (no more staging)
    asm volatile("s_waitcnt lgkmcnt(0)" ::: "memory");
    asm volatile("s_waitcnt vmcnt(2)" ::: "memory");
    __builtin_amdgcn_s_barrier();
    qk(30 & 3); exppv(29 & 3); rot();
    // t = 31 (drain)
    asm volatile("s_waitcnt lgkmcnt(0)" ::: "memory");
    asm volatile("s_waitcnt vmcnt(0)" ::: "memory");
    __builtin_amdgcn_s_barrier();
    qk(31 & 3); exppv(30 & 3); rot();
    // finish tile 31's exp + PV
    exppv(31 & 3);

    // ---- finalize: l is replicated in ol*[r] (ones-MFMA), no shuffle needed
    const float ilA = 1.f / olA[0];
    const float ilB = 1.f / olB[0];

    float* ObA = O + ((size_t)b * L_SEQ + q0) * 64;
    float* ObB = ObA + 64 * 64;
    f32x4 ov;
    #pragma unroll
    for (int r = 0; r < 4; ++r) ov[r] = oA0[r] * ilA;
    *(f32x4*)&ObA[0 * 16 + h * 4] = ov;
    #pragma unroll
    for (int r = 0; r < 4; ++r) ov[r] = oA1[r] * ilA;
    *(f32x4*)&ObA[1 * 16 + h * 4] = ov;
    #pragma unroll
    for (int r = 0; r < 4; ++r) ov[r] = oA2[r] * ilA;
    *(f32x4*)&ObA[2 * 16 + h * 4] = ov;
    #pragma unroll
    for (int r = 0; r < 4; ++r) ov[r] = oA3[r] * ilA;
    *(f32x4*)&ObA[3 * 16 + h * 4] = ov;
    #pragma unroll
    for (int r = 0; r < 4; ++r) ov[r] = oB0[r] * ilB;
    *(f32x4*)&ObB[0 * 16 + h * 4] = ov;
    #pragma unroll
    for (int r = 0; r < 4; ++r) ov[r] = oB1[r] * ilB;
    *(f32x4*)&ObB[1 * 16 + h * 4] = ov;
    #pragma unroll
    for (int r = 0; r < 4; ++r) ov[r] = oB2[r] * ilB;
    *(f32x4*)&ObB[2 * 16 + h * 4] = ov;
    #pragma unroll
    for (int r = 0; r < 4; ++r) ov[r] = oB3[r] * ilB;
    *(f32x4*)&ObB[3 * 16 + h * 4] = ov;
}

// ---------------------------------------------------------------------------
// Fallback (round-1 kernel, verified): used only if ws_size is too small.
// ---------------------------------------------------------------------------
__global__ __launch_bounds__(256) void sdpa_fwd_kernel(
    const float* __restrict__ Q, const float* __restrict__ K,
    const float* __restrict__ V, float* __restrict__ O)
{
    __shared__ __bf16 kt[KVBLK * KSTR];
    __shared__ __bf16 vt[D_HEAD * VSTR];

    const int tid  = threadIdx.x;
    const int lane = tid & 63;
    const int wave = tid >> 6;
    const int li   = lane & 15;
    const int h    = lane >> 4;

    const int b     = blockIdx.x >> 4;
    const int qtile = blockIdx.x & 15;
    const int qrow  = qtile * 64 + wave * 16 + li;

    const float* Qb = Q + (size_t)b * L_SEQ * D_HEAD;
    const float* Kb = K + (size_t)b * L_SEQ * D_HEAD;
    const float* Vb = V + (size_t)b * L_SEQ * D_HEAD;

    bf16x8 qf[2];
    #pragma unroll
    for (int c = 0; c < 2; ++c) {
        #pragma unroll
        for (int hf = 0; hf < 2; ++hf) {
            f32x4 qv = *(const f32x4*)&Qb[(size_t)qrow * D_HEAD + c * 32 + hf * 16 + h * 4];
            #pragma unroll
            for (int j = 0; j < 4; ++j)
                qf[c][hf * 4 + j] = (__bf16)(qv[j] * 0.125f);
        }
    }

    f32x4 oacc[4];
    #pragma unroll
    for (int dc = 0; dc < 4; ++dc) oacc[dc] = (f32x4){0.f, 0.f, 0.f, 0.f};
    float m_run = -1e30f;
    float l_run = 0.f;

    for (int kv = 0; kv < L_SEQ; kv += KVBLK) {
        __syncthreads();
        #pragma unroll
        for (int it = 0; it < 2; ++it) {
            int idx = tid + it * 256;
            int j   = idx >> 4;
            int d4  = (idx & 15) << 2;
            f32x4 x = *(const f32x4*)&Kb[(size_t)(kv + j) * D_HEAD + d4];
            __bf16* dst = &kt[j * KSTR + d4];
            dst[0] = (__bf16)x[0]; dst[1] = (__bf16)x[1];
            dst[2] = (__bf16)x[2]; dst[3] = (__bf16)x[3];
        }
        #pragma unroll
        for (int it = 0; it < 2; ++it) {
            int idx = tid + it * 256;
            int j   = idx >> 4;
            int d4  = (idx & 15) << 2;
            f32x4 x = *(const f32x4*)&Vb[(size_t)(kv + j) * D_HEAD + d4];
            #pragma unroll
            for (int u = 0; u < 4; ++u)
                vt[(d4 + u) * VSTR + j] = (__bf16)x[u];
        }
        __syncthreads();

        f32x4 sacc[2];
        #pragma unroll
        for (int ch = 0; ch < 2; ++ch) {
            sacc[ch] = (f32x4){0.f, 0.f, 0.f, 0.f};
            #pragma unroll
            for (int c = 0; c < 2; ++c) {
                bf16x8 kf;
                #pragma unroll
                for (int hf = 0; hf < 2; ++hf) {
                    bf16x4 k4 = *(const bf16x4*)&kt[(ch * 16 + li) * KSTR + c * 32 + hf * 16 + h * 4];
                    #pragma unroll
                    for (int j = 0; j < 4; ++j) kf[hf * 4 + j] = k4[j];
                }
                sacc[ch] = __builtin_amdgcn_mfma_f32_16x16x32_bf16(kf, qf[c], sacc[ch], 0, 0, 0);
            }
        }

        float tmax = fmaxf(fmaxf(fmaxf(sacc[0][0], sacc[0][1]), fmaxf(sacc[0][2], sacc[0][3])),
                           fmaxf(fmaxf(sacc[1][0], sacc[1][1]), fmaxf(sacc[1][2], sacc[1][3])));
        tmax = fmaxf(tmax, __shfl_xor(tmax, 16, 64));
        tmax = fmaxf(tmax, __shfl_xor(tmax, 32, 64));
        const float m_new = fmaxf(m_run, tmax);
        const float scale = __expf(m_run - m_new);
        m_run = m_new;
        l_run *= scale;
        #pragma unroll
        for (int dc = 0; dc < 4; ++dc) {
            #pragma unroll
            for (int r = 0; r < 4; ++r) oacc[dc][r] *= scale;
        }

        bf16x8 pf;
        float psum = 0.f;
        #pragma unroll
        for (int ch = 0; ch < 2; ++ch) {
            #pragma unroll
            for (int r = 0; r < 4; ++r) {
                float p = __expf(sacc[ch][r] - m_new);
                psum += p;
                pf[ch * 4 + r] = (__bf16)p;
            }
        }
        l_run += psum;

        #pragma unroll
        for (int dc = 0; dc < 4; ++dc) {
            bf16x8 vf;
            #pragma unroll
            for (int hf = 0; hf < 2; ++hf) {
                bf16x4 v4 = *(const bf16x4*)&vt[(dc * 16 + li) * VSTR + hf * 16 + h * 4];
                #pragma unroll
                for (int j = 0; j < 4; ++j) vf[hf * 4 + j] = v4[j];
            }
            oacc[dc] = __builtin_amdgcn_mfma_f32_16x16x32_bf16(vf, pf, oacc[dc], 0, 0, 0);
        }
    }

    l_run += __shfl_xor(l_run, 16, 64);
    l_run += __shfl_xor(l_run, 32, 64);
    const float inv_l = 1.f / l_run;

    float* Ob = O + ((size_t)b * L_SEQ + qrow) * D_HEAD;
    #pragma unroll
    for (int dc = 0; dc < 4; ++dc) {
        f32x4 ov;
        #pragma unroll
        for (int r = 0; r < 4; ++r) ov[r] = oacc[dc][r] * inv_l;
        *(f32x4*)&Ob[dc * 16 + h * 4] = ov;
    }
}

extern "C" void kernel_launch(void* const* d_in, const int* in_sizes, int n_in,
                              void* d_out, int out_size, void* d_ws, size_t ws_size,
                              hipStream_t stream) {
    const float* q = (const float*)d_in[0];
    const float* k = (const float*)d_in[1];
    const float* v = (const float*)d_in[2];
    float* o = (float*)d_out;

    const size_t PRE = (size_t)64 * L_SEQ * 64 * sizeof(__bf16);   // 8.4 MB per array
    if (ws_size >= 2 * PRE) {
        __bf16* Kp = (__bf16*)d_ws;
        __bf16* Vp = (__bf16*)((char*)d_ws + PRE);
        sdpa_prep<<<dim3(6144), dim3(256), 0, stream>>>(k, v, Kp, Vp);
        sdpa_main<<<dim3(512), dim3(256), 0, stream>>>(q, Kp, Vp, o);
    } else {
        sdpa_fwd_kernel<<<dim3(1024), dim3(256), 0, stream>>>(q, k, v, o);
    }
}

// Round 9
// 39.312 us; speedup vs baseline: 1.3223x; 1.3223x over previous
//
#include <hip/hip_runtime.h>
#include <hip/hip_bf16.h>

#define L_SEQ 1024
#define D_HEAD 64
#define NT2 16         // number of 64-row KV tiles
#define KVBLK 32
#define KSTR 72
#define VSTR 36

typedef __attribute__((ext_vector_type(8))) __bf16 bf16x8;
typedef __attribute__((ext_vector_type(4))) __bf16 bf16x4;
typedef __attribute__((ext_vector_type(4))) float f32x4;
typedef unsigned int u32;

#define STAGE16(gsrc, ldst)                                                     \
  __builtin_amdgcn_global_load_lds(                                             \
      (const __attribute__((address_space(1))) u32*)(gsrc),                     \
      (__attribute__((address_space(3))) u32*)(ldst), 16, 0, 0)

__device__ __forceinline__ float fast_exp2(float x) {
#if __has_builtin(__builtin_amdgcn_exp2f)
    return __builtin_amdgcn_exp2f(x);
#else
    return exp2f(x);
#endif
}

#define MFMA16(a, b, c) __builtin_amdgcn_mfma_f32_16x16x32_bf16((a), (b), (c), 0, 0, 0)

// ---------------------------------------------------------------------------
// Pre-pass (unchanged, layouts are 32-row-granular so they serve KVBLK=64):
// K -> bf16 fragment-permuted + XOR-swizzled row-major image (stride 64);
// V -> bf16 V^T images per 32-row tile, chunk-swizzled.
// ---------------------------------------------------------------------------
__global__ __launch_bounds__(256) void sdpa_prep(
    const float* __restrict__ K, const float* __restrict__ V,
    __bf16* __restrict__ Kp, __bf16* __restrict__ Vp)
{
    __shared__ float vt[32][68];   // V tile transpose buffer (padded)
    const int tid = threadIdx.x;

    if (blockIdx.x < 4096) {
        // ---- K path: 1M quads
        const int gid = blockIdx.x * 256 + tid;
        const int row = gid >> 4;               // global row (b*1024 + r)
        const int d4  = (gid & 15) << 2;
        f32x4 x = *(const f32x4*)&K[(size_t)row * 64 + d4];
        const int c32 = d4 >> 5, rem = d4 & 31, hf = rem >> 4, h = (rem & 15) >> 2;
        const int cp = ((c32 * 32 + h * 8) ^ ((row & 7) * 8)) + hf * 4;
        bf16x4 o;
        #pragma unroll
        for (int u = 0; u < 4; ++u) o[u] = (__bf16)x[u];
        *(bf16x4*)&Kp[(size_t)row * 64 + cp] = o;
    } else {
        // ---- V path: one 32x64 tile per block, transpose via LDS
        const int T = blockIdx.x - 4096;        // 0..2047
        const float* src = V + (size_t)T * 2048;
        #pragma unroll
        for (int i = 0; i < 2; ++i) {
            int idx = tid + i * 256;
            int r   = idx >> 4;
            int d4  = (idx & 15) << 2;
            f32x4 x = *(const f32x4*)&src[r * 64 + d4];
            vt[r][d4 + 0] = x[0]; vt[r][d4 + 1] = x[1];
            vt[r][d4 + 2] = x[2]; vt[r][d4 + 3] = x[3];
        }
        __syncthreads();
        #pragma unroll
        for (int i = 0; i < 2; ++i) {
            int w = tid + i * 256;
            int d = w >> 3, comb = w & 7, vh = comb >> 1, vhf = comb & 1;
            const int vhs = vh ^ ((d >> 1) & 3);   // chunk swizzle
            bf16x4 o;
            #pragma unroll
            for (int vj = 0; vj < 4; ++vj)
                o[vj] = (__bf16)vt[vhf * 16 + vh * 4 + vj][d];
            *(bf16x4*)&Vp[(size_t)T * 2048 + d * 32 + vhs * 8 + vhf * 4] = o;
        }
    }
}

// ---------------------------------------------------------------------------
// Main: 1024 blocks x 4 waves (LDS 48KB -> 3 blocks/CU), 16 q-rows/wave,
// KVBLK = 64 -> only 16 iterations (half the barrier/wait fixed cost of R6),
// 3 x 16KB LDS buffers, staging slack = 2 iterations (~2x longer in wall
// time, covers HBM first-touch). No-max exp2 softmax (NBIAS in accumulator
// init), l via ones-MFMA (no VALU adds, no final shuffle).
// ---------------------------------------------------------------------------
__global__ __launch_bounds__(256) void sdpa_main(
    const float* __restrict__ Q, const __bf16* __restrict__ Kp,
    const __bf16* __restrict__ Vp, float* __restrict__ O)
{
    __shared__ __align__(16) char ldsraw[3 * 16384];  // 3 x (K 8KB + V 8KB)

    const int tid  = threadIdx.x;
    const int lane = tid & 63;
    const int wave = tid >> 6;
    const int li   = lane & 15;
    const int h    = lane >> 4;

    // XCD-chunked swizzle: 128 consecutive logical blocks per XCD.
    const int wg = blockIdx.x;
    const int lb = (wg & 7) * 128 + (wg >> 3);
    const int b  = lb >> 4;          // batch
    const int qt = lb & 15;          // 64-row q-tile
    const int q0 = qt * 64 + wave * 16 + li;

    const float*  Qb = Q  + (size_t)b * L_SEQ * 64;
    const char*   Kb = (const char*)(Kp + (size_t)b * L_SEQ * 64);
    const char*   Vb = (const char*)(Vp + (size_t)b * L_SEQ * 64);

    // ---- Q fragments: fold (1/temperature)*log2(e) -> log2-domain scores
    const float QSC = 0.18033688011112042f;   // 0.125 * log2(e)
    bf16x8 qf0, qf1;
    {
        f32x4 a00 = *(const f32x4*)&Qb[(size_t)q0 * 64 + 0  + h * 4];
        f32x4 a01 = *(const f32x4*)&Qb[(size_t)q0 * 64 + 16 + h * 4];
        f32x4 a10 = *(const f32x4*)&Qb[(size_t)q0 * 64 + 32 + h * 4];
        f32x4 a11 = *(const f32x4*)&Qb[(size_t)q0 * 64 + 48 + h * 4];
        #pragma unroll
        for (int j = 0; j < 4; ++j) {
            qf0[j]     = (__bf16)(a00[j] * QSC);
            qf0[4 + j] = (__bf16)(a01[j] * QSC);
            qf1[j]     = (__bf16)(a10[j] * QSC);
            qf1[4 + j] = (__bf16)(a11[j] * QSC);
        }
    }

    bf16x8 ones;
    #pragma unroll
    for (int j = 0; j < 8; ++j) ones[j] = (__bf16)1.0f;

    const float NBIAS = -46.0f;   // log2-domain bias, cancels in O = PV/l
    f32x4 o0 = {0.f,0.f,0.f,0.f}, o1 = {0.f,0.f,0.f,0.f};
    f32x4 o2 = {0.f,0.f,0.f,0.f}, o3 = {0.f,0.f,0.f,0.f};
    f32x4 ol = {0.f,0.f,0.f,0.f};

    // stage 64-row tile t into buffer bi: K 16KB/4 waves + V 16KB/4 waves
    auto stage = [&](int t, int bi) {
        const size_t go = (size_t)t * 8192 + (size_t)wave * 2048 + (size_t)(lane << 4);
        char* dk = ldsraw + bi * 16384 + wave * 2048;
        char* dv = ldsraw + bi * 16384 + 8192 + wave * 2048;
        STAGE16(Kb + go, dk);
        STAGE16(Kb + go + 1024, dk + 1024);
        STAGE16(Vb + go, dv);
        STAGE16(Vb + go + 1024, dv + 1024);
    };

    const int kswz = (li & 7) << 4;
    const int vswz = ((li >> 1) & 3) << 4;

    auto body = [&](int bi) {
        const char* bb = ldsraw + bi * 16384;
        // K fragments: 4 s-chunks x 2 contraction halves (XOR-swizzled image)
        bf16x8 kf00 = *(const bf16x8*)(bb + (0 * 16 + li) * 128 + ((0  + h * 16) ^ kswz));
        bf16x8 kf01 = *(const bf16x8*)(bb + (0 * 16 + li) * 128 + ((64 + h * 16) ^ kswz));
        bf16x8 kf10 = *(const bf16x8*)(bb + (1 * 16 + li) * 128 + ((0  + h * 16) ^ kswz));
        bf16x8 kf11 = *(const bf16x8*)(bb + (1 * 16 + li) * 128 + ((64 + h * 16) ^ kswz));
        bf16x8 kf20 = *(const bf16x8*)(bb + (2 * 16 + li) * 128 + ((0  + h * 16) ^ kswz));
        bf16x8 kf21 = *(const bf16x8*)(bb + (2 * 16 + li) * 128 + ((64 + h * 16) ^ kswz));
        bf16x8 kf30 = *(const bf16x8*)(bb + (3 * 16 + li) * 128 + ((0  + h * 16) ^ kswz));
        bf16x8 kf31 = *(const bf16x8*)(bb + (3 * 16 + li) * 128 + ((64 + h * 16) ^ kswz));
        // V^T fragments: kv-halves A (rows 0..31) and B (rows 32..63)
        const char* va = bb + 8192;
        const char* vc = bb + 12288;
        bf16x8 vfA0 = *(const bf16x8*)(va + (0 * 16 + li) * 64 + ((h * 16) ^ vswz));
        bf16x8 vfA1 = *(const bf16x8*)(va + (1 * 16 + li) * 64 + ((h * 16) ^ vswz));
        bf16x8 vfA2 = *(const bf16x8*)(va + (2 * 16 + li) * 64 + ((h * 16) ^ vswz));
        bf16x8 vfA3 = *(const bf16x8*)(va + (3 * 16 + li) * 64 + ((h * 16) ^ vswz));
        bf16x8 vfB0 = *(const bf16x8*)(vc + (0 * 16 + li) * 64 + ((h * 16) ^ vswz));
        bf16x8 vfB1 = *(const bf16x8*)(vc + (1 * 16 + li) * 64 + ((h * 16) ^ vswz));
        bf16x8 vfB2 = *(const bf16x8*)(vc + (2 * 16 + li) * 64 + ((h * 16) ^ vswz));
        bf16x8 vfB3 = *(const bf16x8*)(vc + (3 * 16 + li) * 64 + ((h * 16) ^ vswz));
        asm volatile("s_waitcnt lgkmcnt(0)" ::: "memory");   // buffer free pre-barrier

        // ---- QK^T: 4 score chunks (kv = ch*16 + 4h + r), bias in acc init
        const f32x4 nb = {NBIAS, NBIAS, NBIAS, NBIAS};
        __builtin_amdgcn_s_setprio(1);
        f32x4 s0 = MFMA16(kf01, qf1, MFMA16(kf00, qf0, nb));
        f32x4 s1 = MFMA16(kf11, qf1, MFMA16(kf10, qf0, nb));
        f32x4 s2 = MFMA16(kf21, qf1, MFMA16(kf20, qf0, nb));
        f32x4 s3 = MFMA16(kf31, qf1, MFMA16(kf30, qf0, nb));
        __builtin_amdgcn_s_setprio(0);

        // ---- exponentiate (no max, no cross-lane)
        bf16x8 pfA, pfB;
        #pragma unroll
        for (int r = 0; r < 4; ++r) {
            pfA[r]     = (__bf16)fast_exp2(s0[r]);
            pfA[4 + r] = (__bf16)fast_exp2(s1[r]);
            pfB[r]     = (__bf16)fast_exp2(s2[r]);
            pfB[4 + r] = (__bf16)fast_exp2(s3[r]);
        }

        // ---- PV: contraction over 64 kv rows = 2 chained MFMA per d-chunk
        __builtin_amdgcn_s_setprio(1);
        o0 = MFMA16(vfB0, pfB, MFMA16(vfA0, pfA, o0));
        o1 = MFMA16(vfB1, pfB, MFMA16(vfA1, pfA, o1));
        o2 = MFMA16(vfB2, pfB, MFMA16(vfA2, pfA, o2));
        o3 = MFMA16(vfB3, pfB, MFMA16(vfA3, pfA, o3));
        ol = MFMA16(ones, pfB, MFMA16(ones, pfA, ol));
        __builtin_amdgcn_s_setprio(0);
    };

    // ---- prologue: tiles 0 and 1 in flight (8 outstanding loads/wave)
    stage(0, 0);
    stage(1, 1);

    #pragma unroll 3
    for (int t = 0; t < NT2 - 2; ++t) {
        asm volatile("s_waitcnt vmcnt(4)" ::: "memory");   // tile t landed
        __builtin_amdgcn_s_barrier();
        stage(t + 2, (t + 2) % 3);   // overwrites buf (t-1): reads drained
        body(t % 3);
    }
    asm volatile("s_waitcnt vmcnt(4)" ::: "memory");       // t = 14
    __builtin_amdgcn_s_barrier();
    body(14 % 3);
    asm volatile("s_waitcnt vmcnt(0)" ::: "memory");       // t = 15 (drain)
    __builtin_amdgcn_s_barrier();
    body(15 % 3);

    // ---- finalize: l replicated in ol[r] (ones-MFMA)
    const float inv_l = 1.f / ol[0];

    float* Ob = O + ((size_t)b * L_SEQ + q0) * 64;
    f32x4 ov;
    #pragma unroll
    for (int r = 0; r < 4; ++r) ov[r] = o0[r] * inv_l;
    *(f32x4*)&Ob[0 * 16 + h * 4] = ov;
    #pragma unroll
    for (int r = 0; r < 4; ++r) ov[r] = o1[r] * inv_l;
    *(f32x4*)&Ob[1 * 16 + h * 4] = ov;
    #pragma unroll
    for (int r = 0; r < 4; ++r) ov[r] = o2[r] * inv_l;
    *(f32x4*)&Ob[2 * 16 + h * 4] = ov;
    #pragma unroll
    for (int r = 0; r < 4; ++r) ov[r] = o3[r] * inv_l;
    *(f32x4*)&Ob[3 * 16 + h * 4] = ov;
}

// ---------------------------------------------------------------------------
// Fallback (round-1 kernel, verified): used only if ws_size is too small.
// ---------------------------------------------------------------------------
__global__ __launch_bounds__(256) void sdpa_fwd_kernel(
    const float* __restrict__ Q, const float* __restrict__ K,
    const float* __restrict__ V, float* __restrict__ O)
{
    __shared__ __bf16 kt[KVBLK * KSTR];
    __shared__ __bf16 vt[D_HEAD * VSTR];

    const int tid  = threadIdx.x;
    const int lane = tid & 63;
    const int wave = tid >> 6;
    const int li   = lane & 15;
    const int h    = lane >> 4;

    const int b     = blockIdx.x >> 4;
    const int qtile = blockIdx.x & 15;
    const int qrow  = qtile * 64 + wave * 16 + li;

    const float* Qb = Q + (size_t)b * L_SEQ * D_HEAD;
    const float* Kb = K + (size_t)b * L_SEQ * D_HEAD;
    const float* Vb = V + (size_t)b * L_SEQ * D_HEAD;

    bf16x8 qf[2];
    #pragma unroll
    for (int c = 0; c < 2; ++c) {
        #pragma unroll
        for (int hf = 0; hf < 2; ++hf) {
            f32x4 qv = *(const f32x4*)&Qb[(size_t)qrow * D_HEAD + c * 32 + hf * 16 + h * 4];
            #pragma unroll
            for (int j = 0; j < 4; ++j)
                qf[c][hf * 4 + j] = (__bf16)(qv[j] * 0.125f);
        }
    }

    f32x4 oacc[4];
    #pragma unroll
    for (int dc = 0; dc < 4; ++dc) oacc[dc] = (f32x4){0.f, 0.f, 0.f, 0.f};
    float m_run = -1e30f;
    float l_run = 0.f;

    for (int kv = 0; kv < L_SEQ; kv += KVBLK) {
        __syncthreads();
        #pragma unroll
        for (int it = 0; it < 2; ++it) {
            int idx = tid + it * 256;
            int j   = idx >> 4;
            int d4  = (idx & 15) << 2;
            f32x4 x = *(const f32x4*)&Kb[(size_t)(kv + j) * D_HEAD + d4];
            __bf16* dst = &kt[j * KSTR + d4];
            dst[0] = (__bf16)x[0]; dst[1] = (__bf16)x[1];
            dst[2] = (__bf16)x[2]; dst[3] = (__bf16)x[3];
        }
        #pragma unroll
        for (int it = 0; it < 2; ++it) {
            int idx = tid + it * 256;
            int j   = idx >> 4;
            int d4  = (idx & 15) << 2;
            f32x4 x = *(const f32x4*)&Vb[(size_t)(kv + j) * D_HEAD + d4];
            #pragma unroll
            for (int u = 0; u < 4; ++u)
                vt[(d4 + u) * VSTR + j] = (__bf16)x[u];
        }
        __syncthreads();

        f32x4 sacc[2];
        #pragma unroll
        for (int ch = 0; ch < 2; ++ch) {
            sacc[ch] = (f32x4){0.f, 0.f, 0.f, 0.f};
            #pragma unroll
            for (int c = 0; c < 2; ++c) {
                bf16x8 kf;
                #pragma unroll
                for (int hf = 0; hf < 2; ++hf) {
                    bf16x4 k4 = *(const bf16x4*)&kt[(ch * 16 + li) * KSTR + c * 32 + hf * 16 + h * 4];
                    #pragma unroll
                    for (int j = 0; j < 4; ++j) kf[hf * 4 + j] = k4[j];
                }
                sacc[ch] = __builtin_amdgcn_mfma_f32_16x16x32_bf16(kf, qf[c], sacc[ch], 0, 0, 0);
            }
        }

        float tmax = fmaxf(fmaxf(fmaxf(sacc[0][0], sacc[0][1]), fmaxf(sacc[0][2], sacc[0][3])),
                           fmaxf(fmaxf(sacc[1][0], sacc[1][1]), fmaxf(sacc[1][2], sacc[1][3])));
        tmax = fmaxf(tmax, __shfl_xor(tmax, 16, 64));
        tmax = fmaxf(tmax, __shfl_xor(tmax, 32, 64));
        const float m_new = fmaxf(m_run, tmax);
        const float scale = __expf(m_run - m_new);
        m_run = m_new;
        l_run *= scale;
        #pragma unroll
        for (int dc = 0; dc < 4; ++dc) {
            #pragma unroll
            for (int r = 0; r < 4; ++r) oacc[dc][r] *= scale;
        }

        bf16x8 pf;
        float psum = 0.f;
        #pragma unroll
        for (int ch = 0; ch < 2; ++ch) {
            #pragma unroll
            for (int r = 0; r < 4; ++r) {
                float p = __expf(sacc[ch][r] - m_new);
                psum += p;
                pf[ch * 4 + r] = (__bf16)p;
            }
        }
        l_run += psum;

        #pragma unroll
        for (int dc = 0; dc < 4; ++dc) {
            bf16x8 vf;
            #pragma unroll
            for (int hf = 0; hf < 2; ++hf) {
                bf16x4 v4 = *(const bf16x4*)&vt[(dc * 16 + li) * VSTR + hf * 16 + h * 4];
                #pragma unroll
                for (int j = 0; j < 4; ++j) vf[hf * 4 + j] = v4[j];
            }
            oacc[dc] = __builtin_amdgcn_mfma_f32_16x16x32_bf16(vf, pf, oacc[dc], 0, 0, 0);
        }
    }

    l_run += __shfl_xor(l_run, 16, 64);
    l_run += __shfl_xor(l_run, 32, 64);
    const float inv_l = 1.f / l_run;

    float* Ob = O + ((size_t)b * L_SEQ + qrow) * D_HEAD;
    #pragma unroll
    for (int dc = 0; dc < 4; ++dc) {
        f32x4 ov;
        #pragma unroll
        for (int r = 0; r < 4; ++r) ov[r] = oacc[dc][r] * inv_l;
        *(f32x4*)&Ob[dc * 16 + h * 4] = ov;
    }
}

extern "C" void kernel_launch(void* const* d_in, const int* in_sizes, int n_in,
                              void* d_out, int out_size, void* d_ws, size_t ws_size,
                              hipStream_t stream) {
    const float* q = (const float*)d_in[0];
    const float* k = (const float*)d_in[1];
    const float* v = (const float*)d_in[2];
    float* o = (float*)d_out;

    const size_t PRE = (size_t)64 * L_SEQ * 64 * sizeof(__bf16);   // 8.4 MB per array
    if (ws_size >= 2 * PRE) {
        __bf16* Kp = (__bf16*)d_ws;
        __bf16* Vp = (__bf16*)((char*)d_ws + PRE);
        sdpa_prep<<<dim3(6144), dim3(256), 0, stream>>>(k, v, Kp, Vp);
        sdpa_main<<<dim3(1024), dim3(256), 0, stream>>>(q, Kp, Vp, o);
    } else {
        sdpa_fwd_kernel<<<dim3(1024), dim3(256), 0, stream>>>(q, k, v, o);
    }
}

// Round 10
// 38.759 us; speedup vs baseline: 1.3412x; 1.0143x over previous
//
#include <hip/hip_runtime.h>
#include <hip/hip_bf16.h>

#define L_SEQ 1024
#define D_HEAD 64
#define NT2 16         // number of 64-row KV tiles
#define KVBLK 32
#define KSTR 72
#define VSTR 36

typedef __attribute__((ext_vector_type(8))) __bf16 bf16x8;
typedef __attribute__((ext_vector_type(4))) __bf16 bf16x4;
typedef __attribute__((ext_vector_type(4))) float f32x4;
typedef unsigned int u32;

#define STAGE16(gsrc, ldst)                                                     \
  __builtin_amdgcn_global_load_lds(                                             \
      (const __attribute__((address_space(1))) u32*)(gsrc),                     \
      (__attribute__((address_space(3))) u32*)(ldst), 16, 0, 0)

__device__ __forceinline__ float fast_exp2(float x) {
#if __has_builtin(__builtin_amdgcn_exp2f)
    return __builtin_amdgcn_exp2f(x);
#else
    return exp2f(x);
#endif
}

#define MFMA16(a, b, c) __builtin_amdgcn_mfma_f32_16x16x32_bf16((a), (b), (c), 0, 0, 0)

// ---------------------------------------------------------------------------
// Pre-pass with XCD AFFINITY: blockIdx is remapped with the same (i&7)-chunk
// swizzle as sdpa_main, so the XCD that WRITES batch b's Kp/Vp tile images is
// the XCD whose L2 serves sdpa_main's READS of batch b (2 MB per XCD, fits
// the 4 MB per-XCD L2). Kernel bodies unchanged from round 9.
// K_pre: [row][c''] c'' = ((c32*32 + h*8) ^ ((row&7)*8)) + hf*4, stride 64
// V_pre: per 32-row tile: [d][ (vh ^ ((d>>1)&3))*8 + vhf*4 + vj ]
// ---------------------------------------------------------------------------
__global__ __launch_bounds__(256) void sdpa_prep(
    const float* __restrict__ K, const float* __restrict__ V,
    __bf16* __restrict__ Kp, __bf16* __restrict__ Vp)
{
    __shared__ float vt[32][68];   // V tile transpose buffer (padded)
    const int tid = threadIdx.x;

    // XCD-affinity remap: XCD x (blocks with i&7 == x) processes batches
    // 8x..8x+7. Per batch: 64 K-blocks (16 rows each) + 32 V-blocks.
    const int i = blockIdx.x;
    const int w = (i & 7) * 768 + (i >> 3);   // 0..6143
    const int batch = w / 96;
    const int r = w % 96;

    if (r < 64) {
        // ---- K block: 16 rows, 256 quads
        const int row = batch * 1024 + r * 16 + (tid >> 4);
        const int d4  = (tid & 15) << 2;
        f32x4 x = *(const f32x4*)&K[(size_t)row * 64 + d4];
        const int c32 = d4 >> 5, rem = d4 & 31, hf = rem >> 4, h = (rem & 15) >> 2;
        const int cp = ((c32 * 32 + h * 8) ^ ((row & 7) * 8)) + hf * 4;
        bf16x4 o;
        #pragma unroll
        for (int u = 0; u < 4; ++u) o[u] = (__bf16)x[u];
        *(bf16x4*)&Kp[(size_t)row * 64 + cp] = o;
    } else {
        // ---- V block: one 32x64 tile, transpose via LDS
        const int T = batch * 32 + (r - 64);    // 0..2047
        const float* src = V + (size_t)T * 2048;
        #pragma unroll
        for (int i2 = 0; i2 < 2; ++i2) {
            int idx = tid + i2 * 256;
            int rr  = idx >> 4;
            int d4  = (idx & 15) << 2;
            f32x4 x = *(const f32x4*)&src[rr * 64 + d4];
            vt[rr][d4 + 0] = x[0]; vt[rr][d4 + 1] = x[1];
            vt[rr][d4 + 2] = x[2]; vt[rr][d4 + 3] = x[3];
        }
        __syncthreads();
        #pragma unroll
        for (int i2 = 0; i2 < 2; ++i2) {
            int wq = tid + i2 * 256;
            int d = wq >> 3, comb = wq & 7, vh = comb >> 1, vhf = comb & 1;
            const int vhs = vh ^ ((d >> 1) & 3);   // chunk swizzle
            bf16x4 o;
            #pragma unroll
            for (int vj = 0; vj < 4; ++vj)
                o[vj] = (__bf16)vt[vhf * 16 + vh * 4 + vj][d];
            *(bf16x4*)&Vp[(size_t)T * 2048 + d * 32 + vhs * 8 + vhf * 4] = o;
        }
    }
}

// ---------------------------------------------------------------------------
// Main (round-9 verbatim): 1024 blocks x 4 waves, 16 q-rows/wave, KVBLK=64,
// 3 x 16KB LDS buffers, counted vmcnt(4), 1 barrier/iter, no-max exp2
// softmax (NBIAS in acc init), l via ones-MFMA.
// ---------------------------------------------------------------------------
__global__ __launch_bounds__(256) void sdpa_main(
    const float* __restrict__ Q, const __bf16* __restrict__ Kp,
    const __bf16* __restrict__ Vp, float* __restrict__ O)
{
    __shared__ __align__(16) char ldsraw[3 * 16384];  // 3 x (K 8KB + V 8KB)

    const int tid  = threadIdx.x;
    const int lane = tid & 63;
    const int wave = tid >> 6;
    const int li   = lane & 15;
    const int h    = lane >> 4;

    // XCD-chunked swizzle: 128 consecutive logical blocks per XCD.
    const int wg = blockIdx.x;
    const int lb = (wg & 7) * 128 + (wg >> 3);
    const int b  = lb >> 4;          // batch
    const int qt = lb & 15;          // 64-row q-tile
    const int q0 = qt * 64 + wave * 16 + li;

    const float*  Qb = Q  + (size_t)b * L_SEQ * 64;
    const char*   Kb = (const char*)(Kp + (size_t)b * L_SEQ * 64);
    const char*   Vb = (const char*)(Vp + (size_t)b * L_SEQ * 64);

    // ---- Q fragments: fold (1/temperature)*log2(e) -> log2-domain scores
    const float QSC = 0.18033688011112042f;   // 0.125 * log2(e)
    bf16x8 qf0, qf1;
    {
        f32x4 a00 = *(const f32x4*)&Qb[(size_t)q0 * 64 + 0  + h * 4];
        f32x4 a01 = *(const f32x4*)&Qb[(size_t)q0 * 64 + 16 + h * 4];
        f32x4 a10 = *(const f32x4*)&Qb[(size_t)q0 * 64 + 32 + h * 4];
        f32x4 a11 = *(const f32x4*)&Qb[(size_t)q0 * 64 + 48 + h * 4];
        #pragma unroll
        for (int j = 0; j < 4; ++j) {
            qf0[j]     = (__bf16)(a00[j] * QSC);
            qf0[4 + j] = (__bf16)(a01[j] * QSC);
            qf1[j]     = (__bf16)(a10[j] * QSC);
            qf1[4 + j] = (__bf16)(a11[j] * QSC);
        }
    }

    bf16x8 ones;
    #pragma unroll
    for (int j = 0; j < 8; ++j) ones[j] = (__bf16)1.0f;

    const float NBIAS = -46.0f;   // log2-domain bias, cancels in O = PV/l
    f32x4 o0 = {0.f,0.f,0.f,0.f}, o1 = {0.f,0.f,0.f,0.f};
    f32x4 o2 = {0.f,0.f,0.f,0.f}, o3 = {0.f,0.f,0.f,0.f};
    f32x4 ol = {0.f,0.f,0.f,0.f};

    // stage 64-row tile t into buffer bi
    auto stage = [&](int t, int bi) {
        const size_t go = (size_t)t * 8192 + (size_t)wave * 2048 + (size_t)(lane << 4);
        char* dk = ldsraw + bi * 16384 + wave * 2048;
        char* dv = ldsraw + bi * 16384 + 8192 + wave * 2048;
        STAGE16(Kb + go, dk);
        STAGE16(Kb + go + 1024, dk + 1024);
        STAGE16(Vb + go, dv);
        STAGE16(Vb + go + 1024, dv + 1024);
    };

    const int kswz = (li & 7) << 4;
    const int vswz = ((li >> 1) & 3) << 4;

    auto body = [&](int bi) {
        const char* bb = ldsraw + bi * 16384;
        // K fragments: 4 s-chunks x 2 contraction halves (XOR-swizzled image)
        bf16x8 kf00 = *(const bf16x8*)(bb + (0 * 16 + li) * 128 + ((0  + h * 16) ^ kswz));
        bf16x8 kf01 = *(const bf16x8*)(bb + (0 * 16 + li) * 128 + ((64 + h * 16) ^ kswz));
        bf16x8 kf10 = *(const bf16x8*)(bb + (1 * 16 + li) * 128 + ((0  + h * 16) ^ kswz));
        bf16x8 kf11 = *(const bf16x8*)(bb + (1 * 16 + li) * 128 + ((64 + h * 16) ^ kswz));
        bf16x8 kf20 = *(const bf16x8*)(bb + (2 * 16 + li) * 128 + ((0  + h * 16) ^ kswz));
        bf16x8 kf21 = *(const bf16x8*)(bb + (2 * 16 + li) * 128 + ((64 + h * 16) ^ kswz));
        bf16x8 kf30 = *(const bf16x8*)(bb + (3 * 16 + li) * 128 + ((0  + h * 16) ^ kswz));
        bf16x8 kf31 = *(const bf16x8*)(bb + (3 * 16 + li) * 128 + ((64 + h * 16) ^ kswz));
        // V^T fragments: kv-halves A (rows 0..31) and B (rows 32..63)
        const char* va = bb + 8192;
        const char* vc = bb + 12288;
        bf16x8 vfA0 = *(const bf16x8*)(va + (0 * 16 + li) * 64 + ((h * 16) ^ vswz));
        bf16x8 vfA1 = *(const bf16x8*)(va + (1 * 16 + li) * 64 + ((h * 16) ^ vswz));
        bf16x8 vfA2 = *(const bf16x8*)(va + (2 * 16 + li) * 64 + ((h * 16) ^ vswz));
        bf16x8 vfA3 = *(const bf16x8*)(va + (3 * 16 + li) * 64 + ((h * 16) ^ vswz));
        bf16x8 vfB0 = *(const bf16x8*)(vc + (0 * 16 + li) * 64 + ((h * 16) ^ vswz));
        bf16x8 vfB1 = *(const bf16x8*)(vc + (1 * 16 + li) * 64 + ((h * 16) ^ vswz));
        bf16x8 vfB2 = *(const bf16x8*)(vc + (2 * 16 + li) * 64 + ((h * 16) ^ vswz));
        bf16x8 vfB3 = *(const bf16x8*)(vc + (3 * 16 + li) * 64 + ((h * 16) ^ vswz));
        asm volatile("s_waitcnt lgkmcnt(0)" ::: "memory");   // buffer free pre-barrier

        // ---- QK^T: 4 score chunks, bias in acc init
        const f32x4 nb = {NBIAS, NBIAS, NBIAS, NBIAS};
        __builtin_amdgcn_s_setprio(1);
        f32x4 s0 = MFMA16(kf01, qf1, MFMA16(kf00, qf0, nb));
        f32x4 s1 = MFMA16(kf11, qf1, MFMA16(kf10, qf0, nb));
        f32x4 s2 = MFMA16(kf21, qf1, MFMA16(kf20, qf0, nb));
        f32x4 s3 = MFMA16(kf31, qf1, MFMA16(kf30, qf0, nb));
        __builtin_amdgcn_s_setprio(0);

        // ---- exponentiate (no max, no cross-lane)
        bf16x8 pfA, pfB;
        #pragma unroll
        for (int r = 0; r < 4; ++r) {
            pfA[r]     = (__bf16)fast_exp2(s0[r]);
            pfA[4 + r] = (__bf16)fast_exp2(s1[r]);
            pfB[r]     = (__bf16)fast_exp2(s2[r]);
            pfB[4 + r] = (__bf16)fast_exp2(s3[r]);
        }

        // ---- PV: contraction over 64 kv rows = 2 chained MFMA per d-chunk
        __builtin_amdgcn_s_setprio(1);
        o0 = MFMA16(vfB0, pfB, MFMA16(vfA0, pfA, o0));
        o1 = MFMA16(vfB1, pfB, MFMA16(vfA1, pfA, o1));
        o2 = MFMA16(vfB2, pfB, MFMA16(vfA2, pfA, o2));
        o3 = MFMA16(vfB3, pfB, MFMA16(vfA3, pfA, o3));
        ol = MFMA16(ones, pfB, MFMA16(ones, pfA, ol));
        __builtin_amdgcn_s_setprio(0);
    };

    // ---- prologue: tiles 0 and 1 in flight (8 outstanding loads/wave)
    stage(0, 0);
    stage(1, 1);

    #pragma unroll 3
    for (int t = 0; t < NT2 - 2; ++t) {
        asm volatile("s_waitcnt vmcnt(4)" ::: "memory");   // tile t landed
        __builtin_amdgcn_s_barrier();
        stage(t + 2, (t + 2) % 3);   // overwrites buf (t-1): reads drained
        body(t % 3);
    }
    asm volatile("s_waitcnt vmcnt(4)" ::: "memory");       // t = 14
    __builtin_amdgcn_s_barrier();
    body(14 % 3);
    asm volatile("s_waitcnt vmcnt(0)" ::: "memory");       // t = 15 (drain)
    __builtin_amdgcn_s_barrier();
    body(15 % 3);

    // ---- finalize: l replicated in ol[r] (ones-MFMA)
    const float inv_l = 1.f / ol[0];

    float* Ob = O + ((size_t)b * L_SEQ + q0) * 64;
    f32x4 ov;
    #pragma unroll
    for (int r = 0; r < 4; ++r) ov[r] = o0[r] * inv_l;
    *(f32x4*)&Ob[0 * 16 + h * 4] = ov;
    #pragma unroll
    for (int r = 0; r < 4; ++r) ov[r] = o1[r] * inv_l;
    *(f32x4*)&Ob[1 * 16 + h * 4] = ov;
    #pragma unroll
    for (int r = 0; r < 4; ++r) ov[r] = o2[r] * inv_l;
    *(f32x4*)&Ob[2 * 16 + h * 4] = ov;
    #pragma unroll
    for (int r = 0; r < 4; ++r) ov[r] = o3[r] * inv_l;
    *(f32x4*)&Ob[3 * 16 + h * 4] = ov;
}

// ---------------------------------------------------------------------------
// Fallback (round-1 kernel, verified): used only if ws_size is too small.
// ---------------------------------------------------------------------------
__global__ __launch_bounds__(256) void sdpa_fwd_kernel(
    const float* __restrict__ Q, const float* __restrict__ K,
    const float* __restrict__ V, float* __restrict__ O)
{
    __shared__ __bf16 kt[KVBLK * KSTR];
    __shared__ __bf16 vt[D_HEAD * VSTR];

    const int tid  = threadIdx.x;
    const int lane = tid & 63;
    const int wave = tid >> 6;
    const int li   = lane & 15;
    const int h    = lane >> 4;

    const int b     = blockIdx.x >> 4;
    const int qtile = blockIdx.x & 15;
    const int qrow  = qtile * 64 + wave * 16 + li;

    const float* Qb = Q + (size_t)b * L_SEQ * D_HEAD;
    const float* Kb = K + (size_t)b * L_SEQ * D_HEAD;
    const float* Vb = V + (size_t)b * L_SEQ * D_HEAD;

    bf16x8 qf[2];
    #pragma unroll
    for (int c = 0; c < 2; ++c) {
        #pragma unroll
        for (int hf = 0; hf < 2; ++hf) {
            f32x4 qv = *(const f32x4*)&Qb[(size_t)qrow * D_HEAD + c * 32 + hf * 16 + h * 4];
            #pragma unroll
            for (int j = 0; j < 4; ++j)
                qf[c][hf * 4 + j] = (__bf16)(qv[j] * 0.125f);
        }
    }

    f32x4 oacc[4];
    #pragma unroll
    for (int dc = 0; dc < 4; ++dc) oacc[dc] = (f32x4){0.f, 0.f, 0.f, 0.f};
    float m_run = -1e30f;
    float l_run = 0.f;

    for (int kv = 0; kv < L_SEQ; kv += KVBLK) {
        __syncthreads();
        #pragma unroll
        for (int it = 0; it < 2; ++it) {
            int idx = tid + it * 256;
            int j   = idx >> 4;
            int d4  = (idx & 15) << 2;
            f32x4 x = *(const f32x4*)&Kb[(size_t)(kv + j) * D_HEAD + d4];
            __bf16* dst = &kt[j * KSTR + d4];
            dst[0] = (__bf16)x[0]; dst[1] = (__bf16)x[1];
            dst[2] = (__bf16)x[2]; dst[3] = (__bf16)x[3];
        }
        #pragma unroll
        for (int it = 0; it < 2; ++it) {
            int idx = tid + it * 256;
            int j   = idx >> 4;
            int d4  = (idx & 15) << 2;
            f32x4 x = *(const f32x4*)&Vb[(size_t)(kv + j) * D_HEAD + d4];
            #pragma unroll
            for (int u = 0; u < 4; ++u)
                vt[(d4 + u) * VSTR + j] = (__bf16)x[u];
        }
        __syncthreads();

        f32x4 sacc[2];
        #pragma unroll
        for (int ch = 0; ch < 2; ++ch) {
            sacc[ch] = (f32x4){0.f, 0.f, 0.f, 0.f};
            #pragma unroll
            for (int c = 0; c < 2; ++c) {
                bf16x8 kf;
                #pragma unroll
                for (int hf = 0; hf < 2; ++hf) {
                    bf16x4 k4 = *(const bf16x4*)&kt[(ch * 16 + li) * KSTR + c * 32 + hf * 16 + h * 4];
                    #pragma unroll
                    for (int j = 0; j < 4; ++j) kf[hf * 4 + j] = k4[j];
                }
                sacc[ch] = __builtin_amdgcn_mfma_f32_16x16x32_bf16(kf, qf[c], sacc[ch], 0, 0, 0);
            }
        }

        float tmax = fmaxf(fmaxf(fmaxf(sacc[0][0], sacc[0][1]), fmaxf(sacc[0][2], sacc[0][3])),
                           fmaxf(fmaxf(sacc[1][0], sacc[1][1]), fmaxf(sacc[1][2], sacc[1][3])));
        tmax = fmaxf(tmax, __shfl_xor(tmax, 16, 64));
        tmax = fmaxf(tmax, __shfl_xor(tmax, 32, 64));
        const float m_new = fmaxf(m_run, tmax);
        const float scale = __expf(m_run - m_new);
        m_run = m_new;
        l_run *= scale;
        #pragma unroll
        for (int dc = 0; dc < 4; ++dc) {
            #pragma unroll
            for (int r = 0; r < 4; ++r) oacc[dc][r] *= scale;
        }

        bf16x8 pf;
        float psum = 0.f;
        #pragma unroll
        for (int ch = 0; ch < 2; ++ch) {
            #pragma unroll
            for (int r = 0; r < 4; ++r) {
                float p = __expf(sacc[ch][r] - m_new);
                psum += p;
                pf[ch * 4 + r] = (__bf16)p;
            }
        }
        l_run += psum;

        #pragma unroll
        for (int dc = 0; dc < 4; ++dc) {
            bf16x8 vf;
            #pragma unroll
            for (int hf = 0; hf < 2; ++hf) {
                bf16x4 v4 = *(const bf16x4*)&vt[(dc * 16 + li) * VSTR + hf * 16 + h * 4];
                #pragma unroll
                for (int j = 0; j < 4; ++j) vf[hf * 4 + j] = v4[j];
            }
            oacc[dc] = __builtin_amdgcn_mfma_f32_16x16x32_bf16(vf, pf, oacc[dc], 0, 0, 0);
        }
    }

    l_run += __shfl_xor(l_run, 16, 64);
    l_run += __shfl_xor(l_run, 32, 64);
    const float inv_l = 1.f / l_run;

    float* Ob = O + ((size_t)b * L_SEQ + qrow) * D_HEAD;
    #pragma unroll
    for (int dc = 0; dc < 4; ++dc) {
        f32x4 ov;
        #pragma unroll
        for (int r = 0; r < 4; ++r) ov[r] = oacc[dc][r] * inv_l;
        *(f32x4*)&Ob[dc * 16 + h * 4] = ov;
    }
}

extern "C" void kernel_launch(void* const* d_in, const int* in_sizes, int n_in,
                              void* d_out, int out_size, void* d_ws, size_t ws_size,
                              hipStream_t stream) {
    const float* q = (const float*)d_in[0];
    const float* k = (const float*)d_in[1];
    const float* v = (const float*)d_in[2];
    float* o = (float*)d_out;

    const size_t PRE = (size_t)64 * L_SEQ * 64 * sizeof(__bf16);   // 8.4 MB per array
    if (ws_size >= 2 * PRE) {
        __bf16* Kp = (__bf16*)d_ws;
        __bf16* Vp = (__bf16*)((char*)d_ws + PRE);
        sdpa_prep<<<dim3(6144), dim3(256), 0, stream>>>(k, v, Kp, Vp);
        sdpa_main<<<dim3(1024), dim3(256), 0, stream>>>(q, Kp, Vp, o);
    } else {
        sdpa_fwd_kernel<<<dim3(1024), dim3(256), 0, stream>>>(q, k, v, o);
    }
}